// Round 2
// baseline (376.186 us; speedup 1.0000x reference)
//
#include <hip/hip_runtime.h>

// Problem constants
#define NN 64
#define CC 64
#define TT 256
#define VV 25
#define RR 8
#define OO 64
#define PLANE 6400  // T*V per (n,c)

// ---------------------------------------------------------------------------
// Kernel A: xsum[n][c][v] = sum_t x[n][c][t][v]
// One block per (n,c), 256 threads = 256 t's. Thread t reads its 25-float row
// directly (contiguous span per wave -> full cache-line use), then butterfly
// shuffle-reduce over 64 lanes, tiny LDS combine across the 4 waves.
// ---------------------------------------------------------------------------
__global__ __launch_bounds__(256) void k_xsum(const float* __restrict__ x,
                                              float* __restrict__ xsum) {
  int nc = blockIdx.x;  // n*64 + c
  int t = threadIdx.x;
  const float* row = x + (size_t)nc * PLANE + t * VV;
  float r[VV];
#pragma unroll
  for (int v = 0; v < VV; ++v) r[v] = row[v];
#pragma unroll
  for (int off = 32; off > 0; off >>= 1) {
#pragma unroll
    for (int v = 0; v < VV; ++v) r[v] += __shfl_xor(r[v], off, 64);
  }
  __shared__ float sred[4][VV];
  int wave = t >> 6, lane = t & 63;
  if (lane == 0) {
#pragma unroll
    for (int v = 0; v < VV; ++v) sred[wave][v] = r[v];
  }
  __syncthreads();
  if (t < VV)
    xsum[nc * VV + t] = (sred[0][t] + sred[1][t]) + (sred[2][t] + sred[3][t]);
}

// ---------------------------------------------------------------------------
// Kernel B: build m (padded [n][o][u][32]) from xsum; also emit w3t[c][o].
// ---------------------------------------------------------------------------
__global__ __launch_bounds__(256) void k_build_m(
    const float* __restrict__ xsum, const float* __restrict__ A,
    const float* __restrict__ w1, const float* __restrict__ b1,
    const float* __restrict__ w2, const float* __restrict__ b2,
    const float* __restrict__ w4, const float* __restrict__ b4,
    const float* __restrict__ w3, float* __restrict__ w3t,
    float* __restrict__ mp) {
  int n = blockIdx.x;
  __shared__ float xs[CC * VV];    // 1600
  __shared__ float sx1[RR * VV];   // 200
  __shared__ float sx2[RR * VV];   // 200
  __shared__ float att[RR * 625];  // 5000
  int tid = threadIdx.x;
  // w3 transpose (all 64 blocks write identical values - benign)
  for (int k = tid; k < CC * OO; k += 256) {
    int c = k >> 6, o = k & 63;
    w3t[k] = w3[o * CC + c];
  }
  const float* xsn = xsum + n * (CC * VV);
  for (int k = tid; k < CC * VV; k += 256) xs[k] = xsn[k];
  __syncthreads();
  if (tid < RR * VV) {
    int r = tid / VV, v = tid % VV;
    float a1 = 0.f, a2 = 0.f;
#pragma unroll
    for (int c = 0; c < CC; ++c) {
      float xv = xs[c * VV + v];
      a1 = fmaf(w1[r * CC + c], xv, a1);
      a2 = fmaf(w2[r * CC + c], xv, a2);
    }
    sx1[tid] = a1 * (1.f / 256.f) + b1[r];
    sx2[tid] = a2 * (1.f / 256.f) + b2[r];
  }
  __syncthreads();
  for (int k = tid; k < RR * 625; k += 256) {
    int r = k / 625, uv = k % 625;
    int u = uv / VV, v = uv % VV;
    att[k] = tanhf(sx1[r * VV + u] - sx2[r * VV + v]);
  }
  __syncthreads();
  for (int k = tid; k < OO * 625; k += 256) {
    int o = k / 625, uv = k % 625;
    int u = uv / VV, v = uv % VV;
    float a = b4[o] + A[uv];
#pragma unroll
    for (int r = 0; r < RR; ++r) a = fmaf(w4[o * RR + r], att[r * 625 + uv], a);
    mp[(((size_t)n * OO + o) * VV + u) * 32 + v] = a;
  }
}

// ---------------------------------------------------------------------------
// Kernel C (fused conv3 + aggregation):
// Block = (n, t-tile of 32). 832 threads (13 waves); logical thread count 800
// = 32 t x 25 v; threads 800..831 duplicate thread 799 (benign).
// Phase 1 (conv): thread owns p=(t,v); acc[o] += w3t[c][o]*x[n][c][p] over c,
//   weights are wave-uniform -> s_load; pure VALU FMA stream.
// Phase 2 (aggr): 5 rounds x 13 o's. All threads deposit acc[o_w]+b3 into
//   s3[w][v*33+t] (conflict-free); wave w (o wave-uniform -> m via s_load)
//   computes out[t][u] = sum_v m[u][v]*x3[t][v] on lanes<32, transposes into
//   s3[w][t*25+u], then all 64 lanes dump coalesced to global.
// ---------------------------------------------------------------------------
__global__ __launch_bounds__(832) void k_fused(const float* __restrict__ x,
                                               const float* __restrict__ w3t,
                                               const float* __restrict__ b3,
                                               const float* __restrict__ mp,
                                               float* __restrict__ out) {
  int tile = blockIdx.x;  // 0..7  (t0 = tile*32)
  int n = blockIdx.y;     // 0..63
  int tid = threadIdx.x;
  int tidc = tid < 800 ? tid : 799;  // clamp padding threads
  int v = tidc % VV;
  int t_loc = tidc / VV;  // 0..31
  int wave = tid >> 6;    // 0..12
  int lane = tid & 63;

  __shared__ float s3[13][825];  // 42.9 KB

  // ---- Phase 1: conv3 ----
  const float* xn = x + (size_t)n * CC * PLANE + tile * 800;
  float acc[OO];
#pragma unroll
  for (int o = 0; o < OO; ++o) acc[o] = 0.f;
  for (int c = 0; c < CC; ++c) {
    float xv = xn[(size_t)c * PLANE + tidc];
    const float* w = w3t + c * OO;  // wave-uniform -> s_load
#pragma unroll
    for (int o = 0; o < OO; ++o) acc[o] = fmaf(w[o], xv, acc[o]);
  }

  // ---- Phase 2: aggregation, 5 rounds of 13 o's ----
  const float* mpn = mp + (size_t)n * OO * (VV * 32);
#pragma unroll
  for (int rnd = 0; rnd < 5; ++rnd) {
    // deposit x3 slices for this round's 13 o's
#pragma unroll
    for (int w = 0; w < 13; ++w) {
      int o = rnd * 13 + w;
      if (o < OO) s3[w][v * 33 + t_loc] = acc[o] + b3[o];
    }
    __syncthreads();
    int o = rnd * 13 + wave;
    bool alive = (o < OO);
    if (alive && lane < 32) {
      int ou = __builtin_amdgcn_readfirstlane(o);
      const float* mrow = mpn + (size_t)ou * (VV * 32);  // wave-uniform
      float xr[VV];
#pragma unroll
      for (int vv = 0; vv < VV; ++vv) xr[vv] = s3[wave][vv * 33 + lane];
#pragma unroll
      for (int u = 0; u < VV; ++u) {
        float a = 0.f;
#pragma unroll
        for (int vv = 0; vv < VV; ++vv) a = fmaf(mrow[u * 32 + vv], xr[vv], a);
        s3[wave][lane * 25 + u] = a;  // [t][u] layout for coalesced dump
      }
    }
    __syncthreads();
    if (alive) {
      float* outp = out + ((size_t)(n * OO + o) * TT + tile * 32) * VV;
#pragma unroll
      for (int k = 0; k < 13; ++k) {
        int idx = k * 64 + lane;
        if (idx < 800) outp[idx] = s3[wave][idx];
      }
    }
    __syncthreads();
  }
}

extern "C" void kernel_launch(void* const* d_in, const int* in_sizes, int n_in,
                              void* d_out, int out_size, void* d_ws,
                              size_t ws_size, hipStream_t stream) {
  const float* x = (const float*)d_in[0];
  const float* A = (const float*)d_in[1];
  const float* w1 = (const float*)d_in[2];
  const float* b1 = (const float*)d_in[3];
  const float* w2 = (const float*)d_in[4];
  const float* b2 = (const float*)d_in[5];
  const float* w3 = (const float*)d_in[6];
  const float* b3 = (const float*)d_in[7];
  const float* w4 = (const float*)d_in[8];
  const float* b4 = (const float*)d_in[9];
  float* out = (float*)d_out;
  float* ws = (float*)d_ws;

  float* xsum = ws;          // 102400 floats
  float* w3t = ws + 102400;  // 4096 floats
  float* mp = ws + 106496;   // 3,276,800 floats (~13.5 MB total)

  k_xsum<<<NN * CC, 256, 0, stream>>>(x, xsum);
  k_build_m<<<NN, 256, 0, stream>>>(xsum, A, w1, b1, w2, b2, w4, b4, w3, w3t,
                                    mp);
  k_fused<<<dim3(8, NN), 832, 0, stream>>>(x, w3t, b3, mp, out);
}